// Round 9
// baseline (1131.653 us; speedup 1.0000x reference)
//
#include <hip/hip_runtime.h>
#include <math.h>

#define BB 16
#define TT 500
#define CC 2048
#define SN 64
#define SD 512
#define NDEN 128        // 16 batches * 8 column-blocks; batch g blocks = {g,16+g,...} all == g mod 8
#define NTHR 512
#define SHIFTC 30.0f
#define SENT 0xFFFFFFFF00000000ull

// ws layout (u64 indices into p64 = d_ws):
//   fast copies: [0, 16384)      = u64 f[2][16][512]   (L2-resident exchange)
//   slow copies: [16384, 32768)  = u64 s[2][16][512]   (device-scope, MALL)
//   float idx 65536+: DACC[16], DSCALE[16], NACC[16], NSCALE[16]  (memset 0)
#define SLOWO 16384
#define WSF_DACC   65536
#define WSF_DSCALE 65552
#define WSF_NACC   65568
#define WSF_NSCALE 65584

// fast path: SE scope — store lands in own XCD L2, load bypasses L1 and reads L2
__device__ __forceinline__ void st_se(unsigned long long* p, unsigned long long v) {
  asm volatile("global_store_dwordx2 %0, %1, off sc0" :: "v"(p), "v"(v) : "memory");
}
__device__ __forceinline__ unsigned long long ld_se(const unsigned long long* p) {
  unsigned long long r;
  asm volatile("global_load_dwordx2 %0, %1, off sc0\n\ts_waitcnt vmcnt(0)"
               : "=v"(r) : "v"(p) : "memory");
  return r;
}
// slow path: device scope (sc1) — write-through to MALL; guaranteed cross-XCD
__device__ __forceinline__ void st_dev(unsigned long long* p, unsigned long long v) {
  asm volatile("global_store_dwordx2 %0, %1, off sc1" :: "v"(p), "v"(v) : "memory");
}
__device__ __forceinline__ unsigned long long ld_dev(const unsigned long long* p) {
  unsigned long long r;
  asm volatile("global_load_dwordx2 %0, %1, off sc1\n\ts_waitcnt vmcnt(0)"
               : "=v"(r) : "v"(p) : "memory");
  return r;
}

__device__ __forceinline__ float wave_max(float v) {
  #pragma unroll
  for (int off = 32; off > 0; off >>= 1) v = fmaxf(v, __shfl_xor(v, off, 64));
  return v;
}
__device__ __forceinline__ float wave_sum(float v) {
  #pragma unroll
  for (int off = 32; off > 0; off >>= 1) v += __shfl_xor(v, off, 64);
  return v;
}
__device__ __forceinline__ unsigned long long pk(unsigned tag, float v) {
  return ((unsigned long long)tag << 32) | (unsigned long long)__float_as_uint(v);
}
__device__ __forceinline__ float clamp30(float v) {
  return fminf(fmaxf(v, -30.f), 30.f);
}

__global__ __launch_bounds__(NTHR, 1) void fsm_fwd(
    const float* __restrict__ x, const int* __restrict__ seqlens,
    const float* __restrict__ nA, const float* __restrict__ nls,
    const float* __restrict__ nlf, const int* __restrict__ npdf,
    const float* __restrict__ dA, const float* __restrict__ dls,
    const float* __restrict__ dlf, const int* __restrict__ dpdf,
    unsigned long long* __restrict__ p64, float* __restrict__ wsf)
{
  __shared__ float prt[2][8][64];   // double-buffered per-wave partials
  __shared__ float pmx[2][8];       // double-buffered per-wave chunk maxes
  const int tid = threadIdx.x;
  const int lane = tid & 63, wv = tid >> 6;

  if (blockIdx.x < NDEN) {
    // ---------------- DEN (shared A, S=512), 1 batch per group --------------
    const int g  = blockIdx.x & 15;     // batch; all 8 blocks of g share blockIdx%8
    const int cb = blockIdx.x >> 4;     // column block (0..7)
    const int j0 = cb * 64;

    unsigned long long* fb0 = p64 + (size_t)g * SD;                  // fast buf 0
    unsigned long long* fb1 = p64 + (size_t)(16 + g) * SD;           // fast buf 1
    unsigned long long* sb0 = p64 + SLOWO + (size_t)g * SD;          // slow buf 0
    unsigned long long* sb1 = p64 + SLOWO + (size_t)(16 + g) * SD;   // slow buf 1

    // SCRUB: every wave sentinels its own fast poll slots (kills stale L2 lines
    // from previous graph replays). Must complete before ANY p0 is published.
    st_se(fb0 + wv * 64 + lane, SENT);
    st_se(fb1 + wv * 64 + lane, SENT);

    // A in registers: lane holds exp(A[wv*64+k][j0+lane]), k=0..63
    float Areg[64];
    {
      const float* Ap = dA + (size_t)(wv * 64) * SD + j0 + lane;
      #pragma unroll
      for (int k = 0; k < 64; ++k)
        Areg[k] = __expf(Ap[(size_t)k * SD]);
    }
    __syncthreads();   // drains vmcnt -> all scrubs are in L2 before p0 publish

    // wave 0 owns the epilogue for this WG's 64 columns
    const int si = j0 + lane;
    int pdfj = 0, sl = 0; float lfj = 0.f, pcur = 0.f, scale = SHIFTC;
    const float* xb = x + (size_t)g * TT * CC;
    if (wv == 0) {
      pdfj = dpdf[si];
      lfj  = dlf[si];
      sl   = seqlens[g];
      float xv = clamp30(xb[pdfj]);
      pcur = __expf(dls[si] + xv - SHIFTC);
      st_dev(sb0 + si, pk(0u, pcur));   // p0: SLOW ONLY (t=1 polls slow-only)
    }
    float lmlag = 0.f;   // lm(p_{t-2}) entering step t; 0 for t=1

    for (int t = 1; t < TT; ++t) {
      const int bi = t & 1;
      unsigned long long* fin  = bi ? fb0 : fb1;
      unsigned long long* sin  = bi ? sb0 : sb1;
      unsigned long long* fout = bi ? fb1 : fb0;
      unsigned long long* sout = bi ? sb1 : sb0;

      // wave0: precompute emission*renorm factor pre-barrier (lag-2 lm)
      float emfac = 0.f;
      if (wv == 0) {
        float xq = clamp30(xb[(size_t)t * CC + pdfj]);
        emfac = __expf(xq - SHIFTC - lmlag);
      }

      // poll own remote chunk (1 tagged u64/lane)
      const unsigned tg = (unsigned)(t - 1);
      unsigned long long* fa = fin + wv * 64 + lane;
      unsigned long long* sa = sin + wv * 64 + lane;
      unsigned long long w;
      if (t == 1) {
        for (;;) {                       // slow-only: stale-proof first step
          w = ld_dev(sa);
          if ((unsigned)(w >> 32) == tg) break;
          __builtin_amdgcn_s_sleep(1);
        }
      } else {
        int k = 0;
        for (;;) {
          w = ld_se(fa);                 // fast: own-XCD L2 (~250 cyc)
          if ((unsigned)(w >> 32) == tg) break;
          if ((++k & 3) == 0) {
            w = ld_dev(sa);              // fallback: guaranteed progress
            if ((unsigned)(w >> 32) == tg) break;
            __builtin_amdgcn_s_sleep(1);
          }
        }
      }
      float pwin = __uint_as_float((unsigned)w);

      // matvec over own i-window (pure VALU, readlane broadcast)
      float q = 0.f;
      #pragma unroll
      for (int k2 = 0; k2 < 64; ++k2) {
        float pv = __uint_as_float(__builtin_amdgcn_readlane(__float_as_uint(pwin), k2));
        q = fmaf(pv, Areg[k2], q);
      }
      prt[bi][wv][lane] = q;
      float cm = wave_max(pwin);
      if (lane == 0) pmx[bi][wv] = cm;
      __syncthreads();   // the one per-step barrier

      if (wv == 0) {
        float s = 0.f;
        #pragma unroll
        for (int r = 0; r < 8; ++r) s += prt[bi][r][lane];
        if (t < sl) {
          pcur = s * emfac;
          scale += SHIFTC + lmlag;
        }
        unsigned long long w64 = pk((unsigned)t, pcur);
        st_se(fout + si, w64);           // fast copy first (critical path)
        st_dev(sout + si, w64);          // slow copy (guarantee)
        float m = pmx[bi][0];            // off critical path
        #pragma unroll
        for (int r = 1; r < 8; ++r) m = fmaxf(m, pmx[bi][r]);
        lmlag = __logf(m);
      }
      // waves 1..7 go straight to polling t+1 (prt/pmx double-buffered)
    }
    if (wv == 0) {
      float part = wave_sum(pcur * __expf(lfj));
      if (lane == 0) {
        atomicAdd(wsf + WSF_DACC + g, part);   // device scope (cross-XCD safe)
        if (cb == 0) wsf[WSF_DSCALE + g] = scale;
      }
    }
  } else {
    // ---------------- NUM (per-batch A, S=64), single wave, pure VALU -------
    const int b = blockIdx.x - NDEN;
    if (wv != 0) return;

    float Areg[64];   // lane holds exp(nA[i][lane]) for all i
    {
      const float* Ap = nA + b * SN * SN + lane;
      #pragma unroll
      for (int i = 0; i < 64; ++i)
        Areg[i] = __expf(Ap[i * SN]);
    }
    const int   pdfj = npdf[b * SN + lane];
    const float lfj  = nlf[b * SN + lane];
    const int   sl   = seqlens[b];
    float xv = clamp30(x[(size_t)b * TT * CC + pdfj]);
    float pcur = __expf(nls[b * SN + lane] + xv - SHIFTC);
    float scale = SHIFTC;

    for (int t = 1; t < TT; ++t) {
      xv = clamp30(x[(size_t)b * TT * CC + (size_t)t * CC + pdfj]);
      float pold = pcur;
      float q = 0.f;
      #pragma unroll
      for (int i = 0; i < 64; ++i) {
        float pi = __uint_as_float(__builtin_amdgcn_readlane(__float_as_uint(pold), i));
        q = fmaf(pi, Areg[i], q);
      }
      float lm = __logf(wave_max(pold));
      if (t < sl) {
        pcur = q * __expf(xv - SHIFTC - lm);
        scale += SHIFTC + lm;
      }
    }
    float part = wave_sum(pcur * __expf(lfj));
    if (lane == 0) {
      wsf[WSF_NACC + b]   = part;
      wsf[WSF_NSCALE + b] = scale;
    }
  }
}

__global__ void fsm_final(const float* __restrict__ wsf, float* __restrict__ out) {
  const int tid = threadIdx.x;
  float v = 0.f;
  if (tid < 16)
    v = -(wsf[WSF_NSCALE + tid] + __logf(wsf[WSF_NACC + tid]));
  else if (tid < 32)
    v = (wsf[WSF_DSCALE + tid - 16] + __logf(wsf[WSF_DACC + tid - 16]));
  v = wave_sum(v);
  if (tid == 0) out[0] = v;  // loss = den_sum - num_sum
}

extern "C" void kernel_launch(void* const* d_in, const int* in_sizes, int n_in,
                              void* d_out, int out_size, void* d_ws, size_t ws_size,
                              hipStream_t stream) {
  const float* x    = (const float*)d_in[0];
  const int*   sql  = (const int*)d_in[1];
  const float* nA   = (const float*)d_in[2];
  const float* nls  = (const float*)d_in[3];
  const float* nlf  = (const float*)d_in[4];
  const int*   npdf = (const int*)d_in[5];
  const float* dA   = (const float*)d_in[6];
  const float* dls  = (const float*)d_in[7];
  const float* dlf  = (const float*)d_in[8];
  const int*   dpdf = (const int*)d_in[9];
  float* out = (float*)d_out;
  unsigned long long* p64 = (unsigned long long*)d_ws;
  float* wsf = (float*)d_ws;
  (void)in_sizes; (void)n_in; (void)out_size; (void)ws_size;

  // zero the accumulators (atomicAdd targets). Slow-region tags rely on 0xAA
  // poison as sentinel; fast-region stale lines are scrubbed in-kernel.
  hipMemsetAsync((char*)d_ws + 262144, 0, 256, stream);
  fsm_fwd<<<NDEN + BB, NTHR, 0, stream>>>(x, sql, nA, nls, nlf, npdf,
                                          dA, dls, dlf, dpdf, p64, wsf);
  fsm_final<<<1, 64, 0, stream>>>(wsf, out);
}